// Round 23
// baseline (109.266 us; speedup 1.0000x reference)
//
#include <hip/hip_runtime.h>
#include <math.h>

// Problem constants: x(256,8192) b,q,e(8192) M(100,8192) out(256,100)
#define NN 8192
#define BB 256
#define CC 100
#define MAX_ITERS 4096

// ---------------------------------------------------------------------------
// Fire kernel: 256-thread blocks = 4 waves; EACH WAVE OWNS ONE COLUMN
// (j = blockIdx*4 + waveid), 4 rows per lane (64 lanes x 4 = all 256 rows).
// Same per-wave structure as r22 (map trajectory computed once per iter,
// shared by 4 band checks) but with proper launch geometry: grid 2048 x 256
// threads -> 8 blocks/CU -> up to 32 waves/CU resident (r22's 64-thread
// blocks managed only ~22% occupancy and starved the SIMDs).
// Per-element semantics bit-identical to r21/r22 (both measured absmax
// 0.00390625):
//   map: m' = (m<b ? m*rb : (1-m)*rob), rb=1.0f/b rob=1.0f/(1-b) hoisted
//        IEEE f32 reciprocals (locked reference flavor, r10)
//   band: med3(m,lo,hi) != m  <=>  (m<lo)||(m>hi); lo=x-e hi=x+e exact subs
//   Brent fast-forward: survivors of a closed cycle never fire;
//   kk += MAX_ITERS - it is detection-time-independent and equals plain
//   counting to the cap (1 + 4096 = 4097 = reference cap).
// ---------------------------------------------------------------------------
__global__ __launch_bounds__(256) void fire_kernel(
    const float* __restrict__ x, const float* __restrict__ bmap,
    const float* __restrict__ qini, const float* __restrict__ eps,
    float* __restrict__ kout)
{
    const int wid  = threadIdx.x >> 6;        // wave id within block
    const int lane = threadIdx.x & 63;
    const int j    = blockIdx.x * 4 + wid;    // this wave's column

    const float bv  = bmap[j];                // uniform across the wave
    const float qv  = qini[j];
    const float ev  = eps[j];
    const float obv = 1.0f - bv;              // exact (Sterbenz)
    const float rb  = 1.0f / bv;              // hoisted IEEE f32 reciprocals
    const float rob = 1.0f / obv;

    float lov[4], hiv[4], kk[4];
    bool  a[4];
    const bool a0 = (qv != 0.0f);             // q==0: never fires
    #pragma unroll
    for (int r = 0; r < 4; ++r) {
        const float xv = x[(size_t)(r * 64 + lane) * NN + j];
        lov[r] = xv - ev;                     // exact f32 subs, same bits as ref
        hiv[r] = xv + ev;
        kk[r]  = 1.0f;
        a[r]   = a0;
    }

    float m = qv, anchor = qv;                // uniform trajectory state
    int   window = 1, steps = 0;
    bool  cycseen = false;

    int it = 0;
    while (it < MAX_ITERS) {
        #pragma unroll
        for (int u = 0; u < 8; ++u) {
            const bool  lt = (m < bv);
            const float pa = m * rb;
            const float pb = (1.0f - m) * rob;
            m = lt ? pa : pb;                 // reference flavor

            cycseen = cycseen || (m == anchor);   // Brent probe
            if (++steps == window) { anchor = m; window <<= 1; steps = 0; }

            #pragma unroll
            for (int r = 0; r < 4; ++r) {
                const bool o = (__builtin_amdgcn_fmed3f(m, lov[r], hiv[r]) != m);
                a[r] = a[r] && o;
                kk[r] += a[r] ? 1.0f : 0.0f;
            }
        }
        it += 8;
        const bool any = a[0] || a[1] || a[2] || a[3];
        if (__ballot(any) == 0ull) break;     // this wave's 256 rows all fired
        if (cycseen) {                        // trajectory periodic ->
            #pragma unroll
            for (int r = 0; r < 4; ++r)
                kk[r] += a[r] ? (float)(MAX_ITERS - it) : 0.0f;
            break;
        }
    }

    #pragma unroll
    for (int r = 0; r < 4; ++r)
        kout[(size_t)(r * 64 + lane) * NN + j] = kk[r];
}

// ---------------------------------------------------------------------------
// Norm kernel (r14/r18/r21 verbatim, proven): blocks 0..255 -> ||k[i]||,
// 256..355 -> ||M[c]||. f64 accumulation; norms[row] = max(sqrt, 1e-8).
// ---------------------------------------------------------------------------
__global__ __launch_bounds__(256) void norm_kernel(
    const float* __restrict__ k, const float* __restrict__ M,
    float* __restrict__ norms)
{
    __shared__ double red[4];
    const int row = blockIdx.x;
    const float* src = (row < BB) ? (k + (size_t)row * NN)
                                  : (M + (size_t)(row - BB) * NN);
    double s = 0.0;
    for (int j = threadIdx.x * 4; j < NN; j += 1024) {
        const float4 v = *(const float4*)(src + j);
        s += (double)v.x * v.x + (double)v.y * v.y
           + (double)v.z * v.z + (double)v.w * v.w;
    }
    #pragma unroll
    for (int off = 32; off; off >>= 1) s += __shfl_down(s, off, 64);
    const int wid = threadIdx.x >> 6, lane = threadIdx.x & 63;
    if (lane == 0) red[wid] = s;
    __syncthreads();
    if (threadIdx.x == 0)
        norms[row] = fmaxf((float)sqrt(red[0] + red[1] + red[2] + red[3]), 1e-8f);
}

// ---------------------------------------------------------------------------
// Logits GEMM kernel (r18/r21 verbatim, proven): block = 8 rows x 5 classes,
// grid 640; one ladder + one barrier; out = dot / (kn * Mn).
// ---------------------------------------------------------------------------
#define TR 8
#define TC 5
__global__ __launch_bounds__(256) void logits_gemm(
    const float* __restrict__ k, const float* __restrict__ M,
    const float* __restrict__ norms, float* __restrict__ out)
{
    __shared__ float red[4][TR][TC];

    const int rt  = blockIdx.x / (CC / TC);
    const int ct  = blockIdx.x % (CC / TC);
    const int r0  = rt * TR, c0 = ct * TC;
    const int tid = threadIdx.x;
    const int wid = tid >> 6, lane = tid & 63;

    float acc[TR][TC];
    #pragma unroll
    for (int r = 0; r < TR; ++r)
        #pragma unroll
        for (int c = 0; c < TC; ++c) acc[r][c] = 0.0f;

    for (int s = 0; s < 8; ++s) {
        const int jj = s * 1024 + tid * 4;
        float4 mv[TC];
        #pragma unroll
        for (int c = 0; c < TC; ++c)
            mv[c] = *(const float4*)(M + (size_t)(c0 + c) * NN + jj);
        #pragma unroll
        for (int r = 0; r < TR; ++r) {
            const float4 kv = *(const float4*)(k + (size_t)(r0 + r) * NN + jj);
            #pragma unroll
            for (int c = 0; c < TC; ++c)
                acc[r][c] += kv.x * mv[c].x + kv.y * mv[c].y
                           + kv.z * mv[c].z + kv.w * mv[c].w;
        }
    }

    #pragma unroll
    for (int off = 32; off; off >>= 1)
        #pragma unroll
        for (int r = 0; r < TR; ++r)
            #pragma unroll
            for (int c = 0; c < TC; ++c)
                acc[r][c] += __shfl_down(acc[r][c], off, 64);
    if (lane == 0)
        #pragma unroll
        for (int r = 0; r < TR; ++r)
            #pragma unroll
            for (int c = 0; c < TC; ++c)
                red[wid][r][c] = acc[r][c];
    __syncthreads();

    if (tid < TR * TC) {
        const int r = tid / TC, c = tid % TC;
        const float d = red[0][r][c] + red[1][r][c] + red[2][r][c] + red[3][r][c];
        out[(size_t)(r0 + r) * CC + (c0 + c)] =
            d / (norms[r0 + r] * norms[BB + c0 + c]);
    }
}

// ===========================================================================
// FALLBACK: round-10 fused kernel, verbatim (proven green), used only if
// ws_size is too small for the k matrix.
// ===========================================================================
__global__ __launch_bounds__(256) void gls_fused_kernel(
    const float* __restrict__ x, const float* __restrict__ bmap,
    const float* __restrict__ qini, const float* __restrict__ eps,
    const float* __restrict__ M, float* __restrict__ out)
{
    __shared__ float k_lds[NN];
    __shared__ double redsh[4];

    const int i   = blockIdx.x;
    const int tid = threadIdx.x;
    const int wid = tid >> 6, lane = tid & 63;

    double sumsq = 0.0;
    for (int s = 0; s < 32; ++s) {
        const int j = tid + 256 * s;
        const float bv = bmap[j];
        const float qv = qini[j];
        const float ev = eps[j];
        const float xv = x[(size_t)i * NN + j];
        const float lov = xv - ev;
        const float hiv = xv + ev;
        const float obv = 1.0f - bv;
        const float rb  = 1.0f / bv;
        const float rob = 1.0f / obv;

        float m  = qv;
        float kk = 1.0f;
        bool  a  = (qv != 0.0f);
        for (int it = 0; a && it < MAX_ITERS; ++it) {
            const bool  lt  = (m < bv);
            const float num = lt ? m  : (1.0f - m);
            const float r   = lt ? rb : rob;
            m = num * r;
            a = (m < lov) || (m > hiv);
            kk += a ? 1.0f : 0.0f;
        }
        k_lds[j] = kk;
        sumsq += (double)kk * (double)kk;
    }

    #pragma unroll
    for (int off = 32; off; off >>= 1) sumsq += __shfl_down(sumsq, off, 64);
    if (lane == 0) redsh[wid] = sumsq;
    __syncthreads();
    const double rn = fmax(sqrt(redsh[0] + redsh[1] + redsh[2] + redsh[3]), 1e-8);

    for (int cc2 = 0; cc2 < 25; ++cc2) {
        const int c = wid * 25 + cc2;
        const float4* Mp = (const float4*)(M + (size_t)c * NN);
        double dot = 0.0, msq = 0.0;
        #pragma unroll 4
        for (int s = 0; s < 32; ++s) {
            const float4 mv = Mp[lane + 64 * s];
            const float4 kv = *(const float4*)(&k_lds[4 * (lane + 64 * s)]);
            dot += (double)kv.x * (double)mv.x + (double)kv.y * (double)mv.y
                 + (double)kv.z * (double)mv.z + (double)kv.w * (double)mv.w;
            msq += (double)mv.x * (double)mv.x + (double)mv.y * (double)mv.y
                 + (double)mv.z * (double)mv.z + (double)mv.w * (double)mv.w;
        }
        #pragma unroll
        for (int off = 32; off; off >>= 1) {
            dot += __shfl_down(dot, off, 64);
            msq += __shfl_down(msq, off, 64);
        }
        if (lane == 0) {
            const double mn = fmax(sqrt(msq), 1e-8);
            out[(size_t)i * CC + c] = (float)(dot / (rn * mn));
        }
    }
}

// ---------------------------------------------------------------------------
extern "C" void kernel_launch(void* const* d_in, const int* in_sizes, int n_in,
                              void* d_out, int out_size, void* d_ws, size_t ws_size,
                              hipStream_t stream) {
    const float* x = (const float*)d_in[0];  // (256, 8192)
    const float* b = (const float*)d_in[1];  // (8192,)
    const float* q = (const float*)d_in[2];  // (8192,)
    const float* e = (const float*)d_in[3];  // (8192,)
    const float* M = (const float*)d_in[4];  // (100, 8192)
    float* out = (float*)d_out;              // (256, 100)

    // ws layout: kbuf | norms[356]
    const size_t need = (size_t)BB * NN * sizeof(float) + (BB + CC) * sizeof(float);
    if (ws_size >= need) {
        float* kbuf  = (float*)d_ws;
        float* norms = kbuf + (size_t)BB * NN;
        fire_kernel<<<dim3(NN / 4), dim3(256), 0, stream>>>(x, b, q, e, kbuf);
        norm_kernel<<<dim3(BB + CC), dim3(256), 0, stream>>>(kbuf, M, norms);
        logits_gemm<<<dim3((BB / TR) * (CC / TC)), dim3(256), 0, stream>>>(kbuf, M, norms, out);
    } else {
        gls_fused_kernel<<<dim3(BB), dim3(256), 0, stream>>>(x, b, q, e, M, out);
    }
}

// Round 24
// 96.100 us; speedup vs baseline: 1.1370x; 1.1370x over previous
//
#include <hip/hip_runtime.h>
#include <math.h>

// Problem constants: x(256,8192) b,q,e(8192) M(100,8192) out(256,100)
#define NN 8192
#define BB 256
#define CC 100
#define MAX_ITERS 4096

// ---------------------------------------------------------------------------
// FINAL (round-21 configuration, measured 96.4 us total; best of 24 rounds).
//
// Fire kernel: wave = one column x 64 rows (lane = row); block = column
// (4 waves cover all 256 rows); grid 8192. Wave-uniform map trajectory with
// Brent cycle detection (r20 ablation: removing it costs +57 us — the
// heavy-tail columns are cycling columns it fast-forwards), v_med3 band
// check, unroll-8 window with deferred exits.
// Cycle fast-forward (bit-exact, detection-time-independent): when the
// wave-uniform trajectory repeats a previously-survived value, surviving
// lanes can never fire; counting every remaining iter gives kk + (4096-it),
// identical to plain iteration to the cap (1 + 4096 = 4097 = ref cap).
// Locked reference flavor (r10): hoisted IEEE f32 reciprocals rb=1.0f/b,
// rob=1.0f/(1-b); m' = (m<b ? m*rb : (1-m)*rob); lo=x-e, hi=x+e exact subs.
// ---------------------------------------------------------------------------
__global__ __launch_bounds__(256) void fire_kernel(
    const float* __restrict__ x, const float* __restrict__ bmap,
    const float* __restrict__ qini, const float* __restrict__ eps,
    float* __restrict__ kout)
{
    const int j    = blockIdx.x;              // column (one per block)
    const int lane = threadIdx.x & 63;
    const int row  = (threadIdx.x & ~63) + lane;   // wave w covers rows 64w..64w+63

    const float bv  = bmap[j];                // uniform across the wave
    const float qv  = qini[j];
    const float ev  = eps[j];
    const float obv = 1.0f - bv;              // exact (Sterbenz)
    const float rb  = 1.0f / bv;              // hoisted IEEE f32 reciprocals
    const float rob = 1.0f / obv;

    const float xv  = x[(size_t)row * NN + j];
    const float lov = xv - ev;                // exact f32 subs, same bits as ref
    const float hiv = xv + ev;

    float m = qv, anchor = qv;                // uniform trajectory state
    int   window = 1, steps = 0;
    float kk = 1.0f;
    bool  a  = (qv != 0.0f);                  // q==0: never fires
    bool  cycseen = false;

    int it = 0;
    while (it < MAX_ITERS) {
        #pragma unroll
        for (int u = 0; u < 8; ++u) {
            const bool  lt = (m < bv);
            const float pa = m * rb;
            const float pb = (1.0f - m) * rob;
            m = lt ? pa : pb;                 // reference flavor

            cycseen = cycseen || (m == anchor);   // Brent probe
            if (++steps == window) { anchor = m; window <<= 1; steps = 0; }

            const bool o = (__builtin_amdgcn_fmed3f(m, lov, hiv) != m);
            a = a && o;
            kk += a ? 1.0f : 0.0f;
        }
        it += 8;
        if (__ballot(a) == 0ull) break;       // all 64 rows fired
        if (cycseen) {                        // trajectory periodic ->
            kk += a ? (float)(MAX_ITERS - it) : 0.0f;  // survivors never fire
            break;
        }
    }

    kout[(size_t)row * NN + j] = kk;
}

// ---------------------------------------------------------------------------
// Norm kernel (r14/r18 verbatim, proven): blocks 0..255 -> ||k[i]||,
// 256..355 -> ||M[c]||. f64 accumulation; norms[row] = max(sqrt, 1e-8).
// ---------------------------------------------------------------------------
__global__ __launch_bounds__(256) void norm_kernel(
    const float* __restrict__ k, const float* __restrict__ M,
    float* __restrict__ norms)
{
    __shared__ double red[4];
    const int row = blockIdx.x;
    const float* src = (row < BB) ? (k + (size_t)row * NN)
                                  : (M + (size_t)(row - BB) * NN);
    double s = 0.0;
    for (int j = threadIdx.x * 4; j < NN; j += 1024) {
        const float4 v = *(const float4*)(src + j);
        s += (double)v.x * v.x + (double)v.y * v.y
           + (double)v.z * v.z + (double)v.w * v.w;
    }
    #pragma unroll
    for (int off = 32; off; off >>= 1) s += __shfl_down(s, off, 64);
    const int wid = threadIdx.x >> 6, lane = threadIdx.x & 63;
    if (lane == 0) red[wid] = s;
    __syncthreads();
    if (threadIdx.x == 0)
        norms[row] = fmaxf((float)sqrt(red[0] + red[1] + red[2] + red[3]), 1e-8f);
}

// ---------------------------------------------------------------------------
// Logits GEMM kernel (r18 verbatim, proven): block = 8 rows x 5 classes,
// grid 640; one ladder + one barrier; out = dot / (kn * Mn).
// ---------------------------------------------------------------------------
#define TR 8
#define TC 5
__global__ __launch_bounds__(256) void logits_gemm(
    const float* __restrict__ k, const float* __restrict__ M,
    const float* __restrict__ norms, float* __restrict__ out)
{
    __shared__ float red[4][TR][TC];

    const int rt  = blockIdx.x / (CC / TC);
    const int ct  = blockIdx.x % (CC / TC);
    const int r0  = rt * TR, c0 = ct * TC;
    const int tid = threadIdx.x;
    const int wid = tid >> 6, lane = tid & 63;

    float acc[TR][TC];
    #pragma unroll
    for (int r = 0; r < TR; ++r)
        #pragma unroll
        for (int c = 0; c < TC; ++c) acc[r][c] = 0.0f;

    for (int s = 0; s < 8; ++s) {
        const int jj = s * 1024 + tid * 4;
        float4 mv[TC];
        #pragma unroll
        for (int c = 0; c < TC; ++c)
            mv[c] = *(const float4*)(M + (size_t)(c0 + c) * NN + jj);
        #pragma unroll
        for (int r = 0; r < TR; ++r) {
            const float4 kv = *(const float4*)(k + (size_t)(r0 + r) * NN + jj);
            #pragma unroll
            for (int c = 0; c < TC; ++c)
                acc[r][c] += kv.x * mv[c].x + kv.y * mv[c].y
                           + kv.z * mv[c].z + kv.w * mv[c].w;
        }
    }

    #pragma unroll
    for (int off = 32; off; off >>= 1)
        #pragma unroll
        for (int r = 0; r < TR; ++r)
            #pragma unroll
            for (int c = 0; c < TC; ++c)
                acc[r][c] += __shfl_down(acc[r][c], off, 64);
    if (lane == 0)
        #pragma unroll
        for (int r = 0; r < TR; ++r)
            #pragma unroll
            for (int c = 0; c < TC; ++c)
                red[wid][r][c] = acc[r][c];
    __syncthreads();

    if (tid < TR * TC) {
        const int r = tid / TC, c = tid % TC;
        const float d = red[0][r][c] + red[1][r][c] + red[2][r][c] + red[3][r][c];
        out[(size_t)(r0 + r) * CC + (c0 + c)] =
            d / (norms[r0 + r] * norms[BB + c0 + c]);
    }
}

// ===========================================================================
// FALLBACK: round-10 fused kernel, verbatim (proven green), used only if
// ws_size is too small for the k matrix.
// ===========================================================================
__global__ __launch_bounds__(256) void gls_fused_kernel(
    const float* __restrict__ x, const float* __restrict__ bmap,
    const float* __restrict__ qini, const float* __restrict__ eps,
    const float* __restrict__ M, float* __restrict__ out)
{
    __shared__ float k_lds[NN];
    __shared__ double redsh[4];

    const int i   = blockIdx.x;
    const int tid = threadIdx.x;
    const int wid = tid >> 6, lane = tid & 63;

    double sumsq = 0.0;
    for (int s = 0; s < 32; ++s) {
        const int j = tid + 256 * s;
        const float bv = bmap[j];
        const float qv = qini[j];
        const float ev = eps[j];
        const float xv = x[(size_t)i * NN + j];
        const float lov = xv - ev;
        const float hiv = xv + ev;
        const float obv = 1.0f - bv;
        const float rb  = 1.0f / bv;
        const float rob = 1.0f / obv;

        float m  = qv;
        float kk = 1.0f;
        bool  a  = (qv != 0.0f);
        for (int it = 0; a && it < MAX_ITERS; ++it) {
            const bool  lt  = (m < bv);
            const float num = lt ? m  : (1.0f - m);
            const float r   = lt ? rb : rob;
            m = num * r;
            a = (m < lov) || (m > hiv);
            kk += a ? 1.0f : 0.0f;
        }
        k_lds[j] = kk;
        sumsq += (double)kk * (double)kk;
    }

    #pragma unroll
    for (int off = 32; off; off >>= 1) sumsq += __shfl_down(sumsq, off, 64);
    if (lane == 0) redsh[wid] = sumsq;
    __syncthreads();
    const double rn = fmax(sqrt(redsh[0] + redsh[1] + redsh[2] + redsh[3]), 1e-8);

    for (int cc2 = 0; cc2 < 25; ++cc2) {
        const int c = wid * 25 + cc2;
        const float4* Mp = (const float4*)(M + (size_t)c * NN);
        double dot = 0.0, msq = 0.0;
        #pragma unroll 4
        for (int s = 0; s < 32; ++s) {
            const float4 mv = Mp[lane + 64 * s];
            const float4 kv = *(const float4*)(&k_lds[4 * (lane + 64 * s)]);
            dot += (double)kv.x * (double)mv.x + (double)kv.y * (double)mv.y
                 + (double)kv.z * (double)mv.z + (double)kv.w * (double)mv.w;
            msq += (double)mv.x * (double)mv.x + (double)mv.y * (double)mv.y
                 + (double)mv.z * (double)mv.z + (double)mv.w * (double)mv.w;
        }
        #pragma unroll
        for (int off = 32; off; off >>= 1) {
            dot += __shfl_down(dot, off, 64);
            msq += __shfl_down(msq, off, 64);
        }
        if (lane == 0) {
            const double mn = fmax(sqrt(msq), 1e-8);
            out[(size_t)i * CC + c] = (float)(dot / (rn * mn));
        }
    }
}

// ---------------------------------------------------------------------------
extern "C" void kernel_launch(void* const* d_in, const int* in_sizes, int n_in,
                              void* d_out, int out_size, void* d_ws, size_t ws_size,
                              hipStream_t stream) {
    const float* x = (const float*)d_in[0];  // (256, 8192)
    const float* b = (const float*)d_in[1];  // (8192,)
    const float* q = (const float*)d_in[2];  // (8192,)
    const float* e = (const float*)d_in[3];  // (8192,)
    const float* M = (const float*)d_in[4];  // (100, 8192)
    float* out = (float*)d_out;              // (256, 100)

    // ws layout: kbuf | norms[356]
    const size_t need = (size_t)BB * NN * sizeof(float) + (BB + CC) * sizeof(float);
    if (ws_size >= need) {
        float* kbuf  = (float*)d_ws;
        float* norms = kbuf + (size_t)BB * NN;
        fire_kernel<<<dim3(NN), dim3(256), 0, stream>>>(x, b, q, e, kbuf);
        norm_kernel<<<dim3(BB + CC), dim3(256), 0, stream>>>(kbuf, M, norms);
        logits_gemm<<<dim3((BB / TR) * (CC / TC)), dim3(256), 0, stream>>>(kbuf, M, norms, out);
    } else {
        gls_fused_kernel<<<dim3(BB), dim3(256), 0, stream>>>(x, b, q, e, M, out);
    }
}